// Round 3
// baseline (248.550 us; speedup 1.0000x reference)
//
#include <hip/hip_runtime.h>
#include <hip/hip_fp16.h>

// Problem constants (from reference)
#define NN 100000
#define KK 32
#define DD 128
// remove = floor(32*0.45) = 14 -> keep sorted ranks [14,18), mean of 4

typedef _Float16 v8h __attribute__((ext_vector_type(8)));
typedef _Float16 v4h __attribute__((ext_vector_type(4)));
typedef _Float16 v2h __attribute__((ext_vector_type(2)));
typedef float    v4f __attribute__((ext_vector_type(4)));
typedef float    v2f __attribute__((ext_vector_type(2)));
typedef int      v4i __attribute__((ext_vector_type(4)));

#define LDH 136   // padded LDS row stride in f16 (128 + 8): 272 B = 17*16 B

// ---------------------------------------------------------------------------
// h layout: 8-way SLICE-MAJOR: h_s[s][n][16] f16, slice s = channels
// [16s, 16s+16), 3.2 MB per slice -- FITS one XCD's 4 MB L2.
// slice = blockIdx & 7 pins each slice to one XCD (blockIdx%8 round-robin).
// nbrs reads and out writes are nontemporal so they don't evict the slice.
// ---------------------------------------------------------------------------

// Kernel 1: h = x @ W^T in f16 via MFMA 16x16x32 (store addressing = 8-slice).
__global__ __launch_bounds__(256)
void gemm_mfma_kernel(const float* __restrict__ x, const float* __restrict__ W,
                      _Float16* __restrict__ h) {
    __shared__ _Float16 w_lds[DD * LDH];
    __shared__ _Float16 x_lds[128 * LDH];

    const int tid = threadIdx.x;
    const int block_row = blockIdx.x * 128;

    {
        const float4* ws = (const float4*)W;
        #pragma unroll
        for (int t = 0; t < 16; ++t) {
            const int fi = tid + 256 * t;
            const int r = fi >> 5, c4 = fi & 31;
            const float4 f = ws[fi];
            v4h p = { (_Float16)f.x, (_Float16)f.y, (_Float16)f.z, (_Float16)f.w };
            *(v4h*)&w_lds[r * LDH + c4 * 4] = p;
        }
    }
    {
        const float4* xs = (const float4*)x;
        #pragma unroll
        for (int t = 0; t < 16; ++t) {
            const int fi = tid + 256 * t;
            const int r = fi >> 5, c4 = fi & 31;
            const int gr = block_row + r;
            float4 f = make_float4(0.f, 0.f, 0.f, 0.f);
            if (gr < NN) f = xs[(size_t)gr * 32 + c4];
            v4h p = { (_Float16)f.x, (_Float16)f.y, (_Float16)f.z, (_Float16)f.w };
            *(v4h*)&x_lds[r * LDH + c4 * 4] = p;
        }
    }
    __syncthreads();

    const int wv   = tid >> 6;
    const int lane = tid & 63;
    const int m    = lane & 15;
    const int quad = lane >> 4;

    const v4f zero = {0.f, 0.f, 0.f, 0.f};
    v4f acc[2][8];
    #pragma unroll
    for (int nt = 0; nt < 2; ++nt)
        #pragma unroll
        for (int ot = 0; ot < 8; ++ot) acc[nt][ot] = zero;

    #pragma unroll
    for (int ks = 0; ks < 4; ++ks) {
        const int kb = ks * 32 + quad * 8;
        const v8h xf0 = *(const v8h*)&x_lds[(wv * 32 + m) * LDH + kb];
        const v8h xf1 = *(const v8h*)&x_lds[(wv * 32 + 16 + m) * LDH + kb];
        #pragma unroll
        for (int ot = 0; ot < 8; ++ot) {
            const v8h wf = *(const v8h*)&w_lds[(ot * 16 + m) * LDH + kb];
            acc[0][ot] = __builtin_amdgcn_mfma_f32_16x16x32_f16(wf, xf0, acc[0][ot], 0, 0, 0);
            acc[1][ot] = __builtin_amdgcn_mfma_f32_16x16x32_f16(wf, xf1, acc[1][ot], 0, 0, 0);
        }
    }

    #pragma unroll
    for (int nt = 0; nt < 2; ++nt) {
        const int xr = block_row + wv * 32 + nt * 16 + m;
        if (xr < NN) {
            #pragma unroll
            for (int ot = 0; ot < 8; ++ot) {
                const v4f a = acc[nt][ot];
                v4h p = { (_Float16)a.x, (_Float16)a.y, (_Float16)a.z, (_Float16)a.w };
                const int c   = ot * 16 + quad * 4;   // global channel of first elem
                const int s   = c >> 4;               // slice 0..7
                const int col = c & 15;               // column within slice
                *(v4h*)&h[((size_t)s * NN + xr) * 16 + col] = p;
            }
        }
    }
}

// ---------------------------------------------------------------------------
// Compile-time Batcher odd-even mergesort network for 16 elements (63 CEs).
// ---------------------------------------------------------------------------
struct CEp { signed char a, b; };
struct Net16 { CEp ce[63]; };

constexpr int oem_merge(CEp* out, int c, int lo, int n, int r) {
    const int m = r * 2;
    if (m < n) {
        c = oem_merge(out, c, lo, n, m);
        c = oem_merge(out, c, lo + r, n, m);
        for (int i = lo + r; i + r < lo + n; i += m) {
            out[c].a = (signed char)i; out[c].b = (signed char)(i + r); ++c;
        }
    } else {
        out[c].a = (signed char)lo; out[c].b = (signed char)(lo + r); ++c;
    }
    return c;
}
constexpr int oem_sort(CEp* out, int c, int lo, int n) {
    if (n > 1) {
        const int m = n / 2;
        c = oem_sort(out, c, lo, m);
        c = oem_sort(out, c, lo + m, m);
        c = oem_merge(out, c, lo, n, 1);
    }
    return c;
}
constexpr Net16 make_net16() {
    Net16 net{};
    (void)oem_sort(net.ce, 0, 0, 16);   // fills exactly 63 CEs
    return net;
}
constexpr Net16 NET16 = make_net16();

// w-index -> v-index map for the final bitonic merge
constexpr int WMAP(int i) { return i < 16 ? i : 47 - i; }

// ---------------------------------------------------------------------------
// Kernel 2: per (row, channel-pair): gather 32 x 4B (2 f16 channels) from the
// XCD-RESIDENT 3.2 MB slice (slice = blockIdx & 7 -> one XCD's L2), sort both
// channels simultaneously with v_pk_min/max_f16, trimmed mean of ranks 14..17.
// Network: 2 x Batcher-16 (63 CE each) + pruned bitonic merge (44 CE) = 170.
//
// Block = 256 threads = 32 rows x 8 channel-pairs. nbrs loads and out stores
// are NONTEMPORAL so the streaming traffic doesn't evict the resident slice.
// Gather coalescing: 8 lanes x 4B = 32 B contiguous per neighbor row.
// ---------------------------------------------------------------------------
#define PKMIN(d, s0, s1) asm("v_pk_min_f16 %0, %1, %2" : "=v"(d) : "v"(s0), "v"(s1))
#define PKMAX(d, s0, s1) asm("v_pk_max_f16 %0, %1, %2" : "=v"(d) : "v"(s0), "v"(s1))

// ascending compare-exchange on v-indices (p gets min, q gets max)
#define CEW(p, q) do {                                                  \
    v2h n_, x_;                                                         \
    PKMIN(n_, va[p], va[q]); PKMAX(x_, va[p], va[q]);                   \
    va[p] = n_; va[q] = x_; } while (0)

__global__ __launch_bounds__(256)
void trimmed_mean_kernel(const _Float16* __restrict__ h, const int* __restrict__ nbrs,
                         float* __restrict__ out) {
    __shared__ int s_nbr[32][33];   // +1 pad: write banks (r*33+c)%32 distinct

    const int tid      = threadIdx.x;
    const int slice    = blockIdx.x & 7;          // one XCD per slice
    const int row_base = (blockIdx.x >> 3) * 32;  // 100000/32 = 3125 exact

    // Load 32 rows x 32 neighbor indices (1024 ints) cooperatively, bypassing
    // L2 allocation (nontemporal) to protect the resident h-slice.
    {
        const v4i v = __builtin_nontemporal_load(
            (const v4i*)(nbrs + (size_t)row_base * KK) + tid);
        const int li = tid * 4;
        const int r = li >> 5, c = li & 31;
        s_nbr[r][c] = v.x; s_nbr[r][c + 1] = v.y;
        s_nbr[r][c + 2] = v.z; s_nbr[r][c + 3] = v.w;
    }
    __syncthreads();

    const int q   = tid & 7;         // channel pair within slice: cols [2q, 2q+2)
    const int r   = tid >> 3;        // row within block, 0..31
    const int row = row_base + r;

    // slice base, in dwords (one dword = 2 f16 channels); row stride = 8 dwords
    const unsigned int* hs = (const unsigned int*)h + (size_t)slice * NN * 8 + q;

    v2h va[KK];
    #pragma unroll
    for (int k = 0; k < KK; ++k) {
        const int idx = s_nbr[r][k];
        va[k] = __builtin_bit_cast(v2h, hs[idx * 8]);
    }

    // Sort both 16-halves ascending (Batcher odd-even mergesort, 63 CE each).
    #pragma unroll
    for (int t = 0; t < 63; ++t) CEW(NET16.ce[t].a, NET16.ce[t].b);
    #pragma unroll
    for (int t = 0; t < 63; ++t) CEW(NET16.ce[t].a + 16, NET16.ce[t].b + 16);

    // Bitonic merge on w = [asc half A, reversed half B], pruned to the
    // middle-4 SET (ranks 14..17 land at w14..w17; internal order irrelevant).
    #pragma unroll
    for (int i = 0; i < 16; ++i) CEW(WMAP(i), WMAP(i + 16));               // j=16
    #pragma unroll
    for (int i = 0; i < 8; ++i) { CEW(WMAP(i), WMAP(i + 8));               // j=8
                                  CEW(WMAP(i + 16), WMAP(i + 24)); }
    #pragma unroll
    for (int i = 8; i < 12; ++i) { CEW(WMAP(i), WMAP(i + 4));              // j=4
                                   CEW(WMAP(i + 8), WMAP(i + 12)); }
    CEW(WMAP(12), WMAP(14)); CEW(WMAP(13), WMAP(15));                      // j=2
    CEW(WMAP(16), WMAP(18)); CEW(WMAP(17), WMAP(19));

    // w14=v[14], w15=v[15], w16=v[31], w17=v[30]
    v2f o;
    o.x = ((float)va[14].x + (float)va[15].x + (float)va[31].x + (float)va[30].x) * 0.25f;
    o.y = ((float)va[14].y + (float)va[15].y + (float)va[31].y + (float)va[30].y) * 0.25f;
    __builtin_nontemporal_store(
        o, (v2f*)(out + (size_t)row * DD + slice * 16) + q);
}

extern "C" void kernel_launch(void* const* d_in, const int* in_sizes, int n_in,
                              void* d_out, int out_size, void* d_ws, size_t ws_size,
                              hipStream_t stream) {
    const float* x    = (const float*)d_in[0];   // (N, 128) fp32
    const float* W    = (const float*)d_in[1];   // (128, 128) fp32
    const int*   nbrs = (const int*)d_in[2];     // (N, 32) int32
    float*       out  = (float*)d_out;           // (N, 128) fp32
    _Float16*    h    = (_Float16*)d_ws;         // scratch: N*128 f16, 8-slice-major

    (void)in_sizes; (void)n_in; (void)out_size; (void)ws_size;

    gemm_mfma_kernel<<<(NN + 127) / 128, 256, 0, stream>>>(x, W, h);       // 782 blocks
    trimmed_mean_kernel<<<(NN / 32) * 8, 256, 0, stream>>>(h, nbrs, out);  // 25000 blocks
}

// Round 5
// 220.873 us; speedup vs baseline: 1.1253x; 1.1253x over previous
//
#include <hip/hip_runtime.h>
#include <hip/hip_fp16.h>

// Problem constants (from reference)
#define NN 100000
#define KK 32
#define DD 128
// remove = floor(32*0.45) = 14 -> keep sorted ranks [14,18), mean of 4

typedef _Float16 v8h __attribute__((ext_vector_type(8)));
typedef _Float16 v4h __attribute__((ext_vector_type(4)));
typedef _Float16 v2h __attribute__((ext_vector_type(2)));
typedef float    v4f __attribute__((ext_vector_type(4)));
typedef int      v4i __attribute__((ext_vector_type(4)));

#define LDH 136   // padded LDS row stride in f16 (128 + 8): 272 B = 17*16 B

// ---------------------------------------------------------------------------
// h layout: 4-way SLICE-MAJOR: h_s[s][n][32] f16, slice s = channels
// [32s, 32s+32). Rows are 64 B -> gathers coalesce into FULL 64 B segments
// (12.8M total transactions; 8-slice's 32 B rows doubled that and lost 35%).
// 6.4 MB/slice is served by the XCD pair {s, s+4} via blockIdx%8 round-robin
// (slice = blockIdx & 3) -> ~60% L2 hit (measured r1). nbrs/out traffic is
// nontemporal so the streams don't evict the slice.
// ---------------------------------------------------------------------------

// Kernel 1: h = x @ W^T in f16 via MFMA 16x16x32 (store addressing = 4-slice).
__global__ __launch_bounds__(256)
void gemm_mfma_kernel(const float* __restrict__ x, const float* __restrict__ W,
                      _Float16* __restrict__ h) {
    __shared__ _Float16 w_lds[DD * LDH];
    __shared__ _Float16 x_lds[128 * LDH];

    const int tid = threadIdx.x;
    const int block_row = blockIdx.x * 128;

    {
        const float4* ws = (const float4*)W;
        #pragma unroll
        for (int t = 0; t < 16; ++t) {
            const int fi = tid + 256 * t;
            const int r = fi >> 5, c4 = fi & 31;
            const float4 f = ws[fi];
            v4h p = { (_Float16)f.x, (_Float16)f.y, (_Float16)f.z, (_Float16)f.w };
            *(v4h*)&w_lds[r * LDH + c4 * 4] = p;
        }
    }
    {
        const float4* xs = (const float4*)x;
        #pragma unroll
        for (int t = 0; t < 16; ++t) {
            const int fi = tid + 256 * t;
            const int r = fi >> 5, c4 = fi & 31;
            const int gr = block_row + r;
            float4 f = make_float4(0.f, 0.f, 0.f, 0.f);
            if (gr < NN) f = xs[(size_t)gr * 32 + c4];
            v4h p = { (_Float16)f.x, (_Float16)f.y, (_Float16)f.z, (_Float16)f.w };
            *(v4h*)&x_lds[r * LDH + c4 * 4] = p;
        }
    }
    __syncthreads();

    const int wv   = tid >> 6;
    const int lane = tid & 63;
    const int m    = lane & 15;
    const int quad = lane >> 4;

    const v4f zero = {0.f, 0.f, 0.f, 0.f};
    v4f acc[2][8];
    #pragma unroll
    for (int nt = 0; nt < 2; ++nt)
        #pragma unroll
        for (int ot = 0; ot < 8; ++ot) acc[nt][ot] = zero;

    #pragma unroll
    for (int ks = 0; ks < 4; ++ks) {
        const int kb = ks * 32 + quad * 8;
        const v8h xf0 = *(const v8h*)&x_lds[(wv * 32 + m) * LDH + kb];
        const v8h xf1 = *(const v8h*)&x_lds[(wv * 32 + 16 + m) * LDH + kb];
        #pragma unroll
        for (int ot = 0; ot < 8; ++ot) {
            const v8h wf = *(const v8h*)&w_lds[(ot * 16 + m) * LDH + kb];
            acc[0][ot] = __builtin_amdgcn_mfma_f32_16x16x32_f16(wf, xf0, acc[0][ot], 0, 0, 0);
            acc[1][ot] = __builtin_amdgcn_mfma_f32_16x16x32_f16(wf, xf1, acc[1][ot], 0, 0, 0);
        }
    }

    #pragma unroll
    for (int nt = 0; nt < 2; ++nt) {
        const int xr = block_row + wv * 32 + nt * 16 + m;
        if (xr < NN) {
            #pragma unroll
            for (int ot = 0; ot < 8; ++ot) {
                const v4f a = acc[nt][ot];
                v4h p = { (_Float16)a.x, (_Float16)a.y, (_Float16)a.z, (_Float16)a.w };
                const int c   = ot * 16 + quad * 4;   // global channel of first elem
                const int s   = c >> 5;               // slice 0..3
                const int col = c & 31;               // column within slice
                *(v4h*)&h[((size_t)s * NN + xr) * 32 + col] = p;
            }
        }
    }
}

// ---------------------------------------------------------------------------
// Compile-time Batcher odd-even mergesort network for 16 elements (63 CEs).
// ---------------------------------------------------------------------------
struct CEp { signed char a, b; };
struct Net16 { CEp ce[63]; };

constexpr int oem_merge(CEp* out, int c, int lo, int n, int r) {
    const int m = r * 2;
    if (m < n) {
        c = oem_merge(out, c, lo, n, m);
        c = oem_merge(out, c, lo + r, n, m);
        for (int i = lo + r; i + r < lo + n; i += m) {
            out[c].a = (signed char)i; out[c].b = (signed char)(i + r); ++c;
        }
    } else {
        out[c].a = (signed char)lo; out[c].b = (signed char)(lo + r); ++c;
    }
    return c;
}
constexpr int oem_sort(CEp* out, int c, int lo, int n) {
    if (n > 1) {
        const int m = n / 2;
        c = oem_sort(out, c, lo, m);
        c = oem_sort(out, c, lo + m, m);
        c = oem_merge(out, c, lo, n, 1);
    }
    return c;
}
constexpr Net16 make_net16() {
    Net16 net{};
    (void)oem_sort(net.ce, 0, 0, 16);   // fills exactly 63 CEs
    return net;
}
constexpr Net16 NET16 = make_net16();

// w-index -> v-index map for the final bitonic merge
constexpr int WMAP(int i) { return i < 16 ? i : 47 - i; }

// ---------------------------------------------------------------------------
// Kernel 2: per (row, channel-quad): gather 32 x 8B (4 f16 channels) from the
// slice (64 B coalesced segments: 8 lanes x 8 B per neighbor row), sort all
// 4 channels simultaneously with v_pk_min/max_f16 (2 register arrays),
// trimmed mean of ranks 14..17.
// Network: 2 x Batcher-16 (63 CE each) + pruned bitonic merge (44 CE) = 170.
//
// Block = 256 threads = 32 rows x 8 channel-quads. 4 ch/thread halves wave
// count vs 2 ch/thread -> halves per-channel addressing + vmem-issue VALU.
// ---------------------------------------------------------------------------
#define PKMIN(d, s0, s1) asm("v_pk_min_f16 %0, %1, %2" : "=v"(d) : "v"(s0), "v"(s1))
#define PKMAX(d, s0, s1) asm("v_pk_max_f16 %0, %1, %2" : "=v"(d) : "v"(s0), "v"(s1))

// ascending compare-exchange on v-indices (p gets min, q gets max)
#define CEW(p, q) do {                                                  \
    v2h na_, xa_, nb_, xb_;                                             \
    PKMIN(na_, va[p], va[q]); PKMAX(xa_, va[p], va[q]);                 \
    PKMIN(nb_, vb[p], vb[q]); PKMAX(xb_, vb[p], vb[q]);                 \
    va[p] = na_; va[q] = xa_; vb[p] = nb_; vb[q] = xb_; } while (0)

__global__ __launch_bounds__(256)
void trimmed_mean_kernel(const _Float16* __restrict__ h, const int* __restrict__ nbrs,
                         float* __restrict__ out) {
    __shared__ int s_nbr[32][33];   // +1 pad: distinct write banks

    const int tid      = threadIdx.x;
    const int slice    = blockIdx.x & 3;          // XCD pair {slice, slice+4}
    const int row_base = (blockIdx.x >> 2) * 32;  // 100000/32 = 3125 exact

    // Load 32 rows x 32 neighbor indices (1024 ints) cooperatively,
    // nontemporal to protect the resident h-slice from eviction.
    {
        const v4i v = __builtin_nontemporal_load(
            (const v4i*)(nbrs + (size_t)row_base * KK) + tid);
        const int li = tid * 4;
        const int r = li >> 5, c = li & 31;
        s_nbr[r][c] = v.x; s_nbr[r][c + 1] = v.y;
        s_nbr[r][c + 2] = v.z; s_nbr[r][c + 3] = v.w;
    }
    __syncthreads();

    const int q   = tid & 7;         // channel quad within slice: [4q, 4q+4)
    const int r   = tid >> 3;        // row within block, 0..31
    const int row = row_base + r;

    // slice base in 8B units; slice row stride = 8 uint2 (32 ch * 2 B = 64 B)
    const uint2* hs = (const uint2*)h + (size_t)slice * NN * 8 + q;

    v2h va[KK];   // channels 4q, 4q+1
    v2h vb[KK];   // channels 4q+2, 4q+3
    #pragma unroll
    for (int k = 0; k < KK; ++k) {
        const int idx = s_nbr[r][k];
        const uint2 u = hs[(size_t)idx * 8];
        va[k] = __builtin_bit_cast(v2h, u.x);
        vb[k] = __builtin_bit_cast(v2h, u.y);
    }

    // Sort both 16-halves ascending (Batcher odd-even mergesort, 63 CE each).
    #pragma unroll
    for (int t = 0; t < 63; ++t) CEW(NET16.ce[t].a, NET16.ce[t].b);
    #pragma unroll
    for (int t = 0; t < 63; ++t) CEW(NET16.ce[t].a + 16, NET16.ce[t].b + 16);

    // Bitonic merge on w = [asc half A, reversed half B], pruned to the
    // middle-4 SET (ranks 14..17 land at w14..w17; internal order irrelevant).
    #pragma unroll
    for (int i = 0; i < 16; ++i) CEW(WMAP(i), WMAP(i + 16));               // j=16
    #pragma unroll
    for (int i = 0; i < 8; ++i) { CEW(WMAP(i), WMAP(i + 8));               // j=8
                                  CEW(WMAP(i + 16), WMAP(i + 24)); }
    #pragma unroll
    for (int i = 8; i < 12; ++i) { CEW(WMAP(i), WMAP(i + 4));              // j=4
                                   CEW(WMAP(i + 8), WMAP(i + 12)); }
    CEW(WMAP(12), WMAP(14)); CEW(WMAP(13), WMAP(15));                      // j=2
    CEW(WMAP(16), WMAP(18)); CEW(WMAP(17), WMAP(19));

    // w14=v[14], w15=v[15], w16=v[31], w17=v[30]
    v4f o;
    o.x = ((float)va[14].x + (float)va[15].x + (float)va[31].x + (float)va[30].x) * 0.25f;
    o.y = ((float)va[14].y + (float)va[15].y + (float)va[31].y + (float)va[30].y) * 0.25f;
    o.z = ((float)vb[14].x + (float)vb[15].x + (float)vb[31].x + (float)vb[30].x) * 0.25f;
    o.w = ((float)vb[14].y + (float)vb[15].y + (float)vb[31].y + (float)vb[30].y) * 0.25f;
    __builtin_nontemporal_store(
        o, (v4f*)(out + (size_t)row * DD + slice * 32) + q);
}

extern "C" void kernel_launch(void* const* d_in, const int* in_sizes, int n_in,
                              void* d_out, int out_size, void* d_ws, size_t ws_size,
                              hipStream_t stream) {
    const float* x    = (const float*)d_in[0];   // (N, 128) fp32
    const float* W    = (const float*)d_in[1];   // (128, 128) fp32
    const int*   nbrs = (const int*)d_in[2];     // (N, 32) int32
    float*       out  = (float*)d_out;           // (N, 128) fp32
    _Float16*    h    = (_Float16*)d_ws;         // scratch: N*128 f16, 4-slice-major

    (void)in_sizes; (void)n_in; (void)out_size; (void)ws_size;

    gemm_mfma_kernel<<<(NN + 127) / 128, 256, 0, stream>>>(x, W, h);       // 782 blocks
    trimmed_mean_kernel<<<(NN / 32) * 4, 256, 0, stream>>>(h, nbrs, out);  // 12500 blocks
}

// Round 7
// 210.475 us; speedup vs baseline: 1.1809x; 1.0494x over previous
//
#include <hip/hip_runtime.h>
#include <hip/hip_fp16.h>

// Problem constants (from reference)
#define NN 100000
#define KK 32
#define DD 128
// remove = floor(32*0.45) = 14 -> keep sorted ranks [14,18), mean of 4

typedef _Float16 v8h __attribute__((ext_vector_type(8)));
typedef _Float16 v4h __attribute__((ext_vector_type(4)));
typedef _Float16 v2h __attribute__((ext_vector_type(2)));
typedef float    v4f __attribute__((ext_vector_type(4)));
typedef int      v2i __attribute__((ext_vector_type(2)));

#define LDH 136   // padded LDS row stride in f16 (128 + 8): 272 B = 17*16 B

// ---------------------------------------------------------------------------
// h layout: 2-way SLICE-MAJOR: h_s[s][n][64] f16, slice s = channels
// [64s, 64s+64). Rows are 128 B = ONE TCP (L1) line -> a row gather is a
// single 128 B line-request instead of two 64 B ones: 6.4M total requests
// vs 12.8M for 64 B rows. Request count is the measured binder
// (r1/r3/r5: dur tracks line-count at ~8 us per M-request, not fetch BW,
// not VALU). Residency drops (12.8 MB/slice over 4 XCDs, ~31% L2 hit) --
// accepted: r3 showed the request/fetch trade is steeply request-dominated.
// slice = blockIdx & 1 -> slice 0 on even XCDs, slice 1 on odd XCDs.
// ---------------------------------------------------------------------------

// Kernel 1: h = x @ W^T in f16 via MFMA 16x16x32 (store addressing = 2-slice).
__global__ __launch_bounds__(256)
void gemm_mfma_kernel(const float* __restrict__ x, const float* __restrict__ W,
                      _Float16* __restrict__ h) {
    __shared__ _Float16 w_lds[DD * LDH];
    __shared__ _Float16 x_lds[128 * LDH];

    const int tid = threadIdx.x;
    const int block_row = blockIdx.x * 128;

    {
        const float4* ws = (const float4*)W;
        #pragma unroll
        for (int t = 0; t < 16; ++t) {
            const int fi = tid + 256 * t;
            const int r = fi >> 5, c4 = fi & 31;
            const float4 f = ws[fi];
            v4h p = { (_Float16)f.x, (_Float16)f.y, (_Float16)f.z, (_Float16)f.w };
            *(v4h*)&w_lds[r * LDH + c4 * 4] = p;
        }
    }
    {
        const float4* xs = (const float4*)x;
        #pragma unroll
        for (int t = 0; t < 16; ++t) {
            const int fi = tid + 256 * t;
            const int r = fi >> 5, c4 = fi & 31;
            const int gr = block_row + r;
            float4 f = make_float4(0.f, 0.f, 0.f, 0.f);
            if (gr < NN) f = xs[(size_t)gr * 32 + c4];
            v4h p = { (_Float16)f.x, (_Float16)f.y, (_Float16)f.z, (_Float16)f.w };
            *(v4h*)&x_lds[r * LDH + c4 * 4] = p;
        }
    }
    __syncthreads();

    const int wv   = tid >> 6;
    const int lane = tid & 63;
    const int m    = lane & 15;
    const int quad = lane >> 4;

    const v4f zero = {0.f, 0.f, 0.f, 0.f};
    v4f acc[2][8];
    #pragma unroll
    for (int nt = 0; nt < 2; ++nt)
        #pragma unroll
        for (int ot = 0; ot < 8; ++ot) acc[nt][ot] = zero;

    #pragma unroll
    for (int ks = 0; ks < 4; ++ks) {
        const int kb = ks * 32 + quad * 8;
        const v8h xf0 = *(const v8h*)&x_lds[(wv * 32 + m) * LDH + kb];
        const v8h xf1 = *(const v8h*)&x_lds[(wv * 32 + 16 + m) * LDH + kb];
        #pragma unroll
        for (int ot = 0; ot < 8; ++ot) {
            const v8h wf = *(const v8h*)&w_lds[(ot * 16 + m) * LDH + kb];
            acc[0][ot] = __builtin_amdgcn_mfma_f32_16x16x32_f16(wf, xf0, acc[0][ot], 0, 0, 0);
            acc[1][ot] = __builtin_amdgcn_mfma_f32_16x16x32_f16(wf, xf1, acc[1][ot], 0, 0, 0);
        }
    }

    #pragma unroll
    for (int nt = 0; nt < 2; ++nt) {
        const int xr = block_row + wv * 32 + nt * 16 + m;
        if (xr < NN) {
            #pragma unroll
            for (int ot = 0; ot < 8; ++ot) {
                const v4f a = acc[nt][ot];
                v4h p = { (_Float16)a.x, (_Float16)a.y, (_Float16)a.z, (_Float16)a.w };
                const int c   = ot * 16 + quad * 4;   // global channel of first elem
                const int s   = c >> 6;               // slice 0..1
                const int col = c & 63;               // column within slice
                *(v4h*)&h[((size_t)s * NN + xr) * 64 + col] = p;
            }
        }
    }
}

// ---------------------------------------------------------------------------
// Compile-time Batcher odd-even mergesort network for 16 elements (63 CEs).
// ---------------------------------------------------------------------------
struct CEp { signed char a, b; };
struct Net16 { CEp ce[63]; };

constexpr int oem_merge(CEp* out, int c, int lo, int n, int r) {
    const int m = r * 2;
    if (m < n) {
        c = oem_merge(out, c, lo, n, m);
        c = oem_merge(out, c, lo + r, n, m);
        for (int i = lo + r; i + r < lo + n; i += m) {
            out[c].a = (signed char)i; out[c].b = (signed char)(i + r); ++c;
        }
    } else {
        out[c].a = (signed char)lo; out[c].b = (signed char)(lo + r); ++c;
    }
    return c;
}
constexpr int oem_sort(CEp* out, int c, int lo, int n) {
    if (n > 1) {
        const int m = n / 2;
        c = oem_sort(out, c, lo, m);
        c = oem_sort(out, c, lo + m, m);
        c = oem_merge(out, c, lo, n, 1);
    }
    return c;
}
constexpr Net16 make_net16() {
    Net16 net{};
    (void)oem_sort(net.ce, 0, 0, 16);   // fills exactly 63 CEs
    return net;
}
constexpr Net16 NET16 = make_net16();

// w-index -> v-index map for the final bitonic merge
constexpr int WMAP(int i) { return i < 16 ? i : 47 - i; }

// ---------------------------------------------------------------------------
// Kernel 2: per (row, channel-quad): gather 32 x 8B (4 f16 channels) from the
// slice. 16 lanes x 8 B = one FULL 128 B row = one L1-line request per
// neighbor row (4 requests per wave-gather instr, 6.4M total). Sort all 4
// channels simultaneously with v_pk_min/max_f16 (2 register arrays),
// trimmed mean of ranks 14..17.
// Network: 2 x Batcher-16 (63 CE each) + pruned bitonic merge (44 CE) = 170.
//
// Block = 256 threads = 16 rows x 16 channel-quads; slice = blockIdx & 1.
// nbrs loads / out stores nontemporal (protect resident h in L2).
// ---------------------------------------------------------------------------
#define PKMIN(d, s0, s1) asm("v_pk_min_f16 %0, %1, %2" : "=v"(d) : "v"(s0), "v"(s1))
#define PKMAX(d, s0, s1) asm("v_pk_max_f16 %0, %1, %2" : "=v"(d) : "v"(s0), "v"(s1))

// ascending compare-exchange on v-indices (p gets min, q gets max)
#define CEW(p, q) do {                                                  \
    v2h na_, xa_, nb_, xb_;                                             \
    PKMIN(na_, va[p], va[q]); PKMAX(xa_, va[p], va[q]);                 \
    PKMIN(nb_, vb[p], vb[q]); PKMAX(xb_, vb[p], vb[q]);                 \
    va[p] = na_; va[q] = xa_; vb[p] = nb_; vb[q] = xb_; } while (0)

__global__ __launch_bounds__(256)
void trimmed_mean_kernel(const _Float16* __restrict__ h, const int* __restrict__ nbrs,
                         float* __restrict__ out) {
    __shared__ int s_nbr[16][33];   // +1 pad: distinct write banks

    const int tid      = threadIdx.x;
    const int slice    = blockIdx.x & 1;          // even XCDs: s0, odd XCDs: s1
    const int row_base = (blockIdx.x >> 1) * 16;  // 100000/16 = 6250 exact

    // Load 16 rows x 32 neighbor indices (512 ints) cooperatively,
    // nontemporal to protect the resident h-slice from eviction.
    {
        const v2i v = __builtin_nontemporal_load(
            (const v2i*)(nbrs + (size_t)row_base * KK) + tid);
        const int li = tid * 2;
        const int r = li >> 5, c = li & 31;
        s_nbr[r][c] = v.x; s_nbr[r][c + 1] = v.y;
    }
    __syncthreads();

    const int q   = tid & 15;        // channel quad within slice: [4q, 4q+4)
    const int r   = tid >> 4;        // row within block, 0..15
    const int row = row_base + r;

    // slice base in 8B units; slice row stride = 16 uint2 (64 ch * 2 B = 128 B)
    const uint2* hs = (const uint2*)h + (size_t)slice * NN * 16 + q;

    v2h va[KK];   // channels 4q, 4q+1
    v2h vb[KK];   // channels 4q+2, 4q+3
    #pragma unroll
    for (int k = 0; k < KK; ++k) {
        const int idx = s_nbr[r][k];
        const uint2 u = hs[(size_t)idx * 16];
        va[k] = __builtin_bit_cast(v2h, u.x);
        vb[k] = __builtin_bit_cast(v2h, u.y);
    }

    // Sort both 16-halves ascending (Batcher odd-even mergesort, 63 CE each).
    #pragma unroll
    for (int t = 0; t < 63; ++t) CEW(NET16.ce[t].a, NET16.ce[t].b);
    #pragma unroll
    for (int t = 0; t < 63; ++t) CEW(NET16.ce[t].a + 16, NET16.ce[t].b + 16);

    // Bitonic merge on w = [asc half A, reversed half B], pruned to the
    // middle-4 SET (ranks 14..17 land at w14..w17; internal order irrelevant).
    #pragma unroll
    for (int i = 0; i < 16; ++i) CEW(WMAP(i), WMAP(i + 16));               // j=16
    #pragma unroll
    for (int i = 0; i < 8; ++i) { CEW(WMAP(i), WMAP(i + 8));               // j=8
                                  CEW(WMAP(i + 16), WMAP(i + 24)); }
    #pragma unroll
    for (int i = 8; i < 12; ++i) { CEW(WMAP(i), WMAP(i + 4));              // j=4
                                   CEW(WMAP(i + 8), WMAP(i + 12)); }
    CEW(WMAP(12), WMAP(14)); CEW(WMAP(13), WMAP(15));                      // j=2
    CEW(WMAP(16), WMAP(18)); CEW(WMAP(17), WMAP(19));

    // w14=v[14], w15=v[15], w16=v[31], w17=v[30]
    v4f o;
    o.x = ((float)va[14].x + (float)va[15].x + (float)va[31].x + (float)va[30].x) * 0.25f;
    o.y = ((float)va[14].y + (float)va[15].y + (float)va[31].y + (float)va[30].y) * 0.25f;
    o.z = ((float)vb[14].x + (float)vb[15].x + (float)vb[31].x + (float)vb[30].x) * 0.25f;
    o.w = ((float)vb[14].y + (float)vb[15].y + (float)vb[31].y + (float)vb[30].y) * 0.25f;
    __builtin_nontemporal_store(
        o, (v4f*)(out + (size_t)row * DD + slice * 64) + q);
}

extern "C" void kernel_launch(void* const* d_in, const int* in_sizes, int n_in,
                              void* d_out, int out_size, void* d_ws, size_t ws_size,
                              hipStream_t stream) {
    const float* x    = (const float*)d_in[0];   // (N, 128) fp32
    const float* W    = (const float*)d_in[1];   // (128, 128) fp32
    const int*   nbrs = (const int*)d_in[2];     // (N, 32) int32
    float*       out  = (float*)d_out;           // (N, 128) fp32
    _Float16*    h    = (_Float16*)d_ws;         // scratch: N*128 f16, 2-slice-major

    (void)in_sizes; (void)n_in; (void)out_size; (void)ws_size;

    gemm_mfma_kernel<<<(NN + 127) / 128, 256, 0, stream>>>(x, W, h);       // 782 blocks
    trimmed_mean_kernel<<<(NN / 16) * 2, 256, 0, stream>>>(h, nbrs, out);  // 12500 blocks
}